// Round 10
// baseline (123.091 us; speedup 1.0000x reference)
//
#include <hip/hip_runtime.h>
#include <hip/hip_bf16.h>

namespace {
constexpr int B   = 16;
constexpr int NS  = 1000;
constexpr int IN  = 128;
constexpr int OUT = 128;
constexpr int K   = 256;   // IN + OUT

typedef __attribute__((ext_vector_type(8))) short short8;
typedef __attribute__((ext_vector_type(4))) float f32x4;

__device__ __forceinline__ float fsigmoid(float x) {
  return 1.0f / (1.0f + __expf(-x));
}
__device__ __forceinline__ float ftanh(float x) {
  return 2.0f / (1.0f + __expf(-2.0f * x)) - 1.0f;
}
// fp32 -> bf16 round-to-nearest-even (bit pattern)
__device__ __forceinline__ unsigned int f2bf(float f) {
  unsigned int u = __builtin_bit_cast(unsigned int, f);
  u += 0x7fffu + ((u >> 16) & 1u);
  return u >> 16;
}
__device__ __forceinline__ unsigned int pack2(float lo, float hi) {
  return f2bf(lo) | (f2bf(hi) << 16);
}
// W slice: [4 kq][64 col][16B]; quad-swizzle spreads cols across bank quads.
__device__ __forceinline__ int slice_addr(int base, int kq, int col) {
  return base + (kq << 10) + ((col << 4) ^ (((col >> 3) & 7) << 4));
}

// Block = (stock n, col half). 4 waves = 4 gates; each wave: C[16 b x 64 col].
// LDS arena (24576 B):
//  [0,8192)      xh bf16 [16 b][256 k], row stride 512B, byte XOR ((b&7)<<4)
//  [8192,24576)  4 per-gate W slices (4KB @ g*4096), layout per slice_addr.
//  Epilogue overlay from 0: gbuf f32, idx = g*1040 + b*65 + coll (16.6 KB).
__global__ __launch_bounds__(256, 6) void lstm_kernel(
    const float* __restrict__ xt, const float* __restrict__ hidden,
    const float* __restrict__ ct_1,
    const float* __restrict__ Wi, const float* __restrict__ bi,
    const float* __restrict__ Wo, const float* __restrict__ bo,
    const float* __restrict__ Wf, const float* __restrict__ bfp,
    const float* __restrict__ Wc, const float* __restrict__ bc,
    float* __restrict__ out) {
  __shared__ __align__(16) unsigned char smem[24576];

  const int bid  = blockIdx.x;
  const int n    = bid >> 1;
  const int half = bid & 1;         // cols half*64 .. +63
  const int tid  = threadIdx.x;

  // ---- stage xh = concat(xt[:,n,:], hidden[0,n,:]) as bf16, swizzled ----
  #pragma unroll
  for (int r = 0; r < 2; ++r) {
    const int idx = tid + (r << 8);   // 0..511
    const int b   = idx >> 5;         // 0..15
    const int s   = idx & 31;         // 16B segment: k0 = s*8
    const int k0  = s << 3;
    float v[8];
    if (k0 < IN) {
      const float4 a = *reinterpret_cast<const float4*>(xt + ((size_t)b * NS + n) * IN + k0);
      const float4 c = *reinterpret_cast<const float4*>(xt + ((size_t)b * NS + n) * IN + k0 + 4);
      v[0]=a.x; v[1]=a.y; v[2]=a.z; v[3]=a.w; v[4]=c.x; v[5]=c.y; v[6]=c.z; v[7]=c.w;
    } else {
      const float4 a = *reinterpret_cast<const float4*>(hidden + (size_t)n * OUT + (k0 - IN));
      const float4 c = *reinterpret_cast<const float4*>(hidden + (size_t)n * OUT + (k0 - IN) + 4);
      v[0]=a.x; v[1]=a.y; v[2]=a.z; v[3]=a.w; v[4]=c.x; v[5]=c.y; v[6]=c.z; v[7]=c.w;
    }
    uint4 pk;
    pk.x = pack2(v[0], v[1]); pk.y = pack2(v[2], v[3]);
    pk.z = pack2(v[4], v[5]); pk.w = pack2(v[6], v[7]);
    const int addr = ((b << 9) + (s << 4)) ^ ((b & 7) << 4);
    *reinterpret_cast<uint4*>(&smem[addr]) = pk;
  }
  __syncthreads();

  const int g   = tid >> 6;   // gate 0..3 (one wave per gate)
  const int l   = tid & 63;
  const int g2  = l >> 4;     // row-quad in loads / k-octet in frags
  const int c16 = l & 15;     // col-quad in loads / frag col

  const float* Wg = (g == 0) ? Wi : (g == 1) ? Wo : (g == 2) ? Wf : Wc;
  const float* bg = (g == 0) ? bi : (g == 1) ? bo : (g == 2) ? bfp : bc;
  // lane's load base: cols half*64 + c16*4 .. +3, rows (sub-stage)*16 + g2*4 + i
  const float* wbase = Wg + (size_t)n * (K * OUT) + half * 64 + (c16 << 2);

  const int wsl = 8192 + (g << 12);  // this gate's 4KB slice (wave-private)
  f32x4 acc[4] = {f32x4{0,0,0,0}, f32x4{0,0,0,0}, f32x4{0,0,0,0}, f32x4{0,0,0,0}};

  // ---- prologue: wqa <- rows 0..15, wqb <- rows 16..31 (8 dwordx4 in flight) ----
  float4 wqa[4], wqb[4];
  #pragma unroll
  for (int i = 0; i < 4; ++i)
    wqa[i] = *reinterpret_cast<const float4*>(wbase + (size_t)((g2 << 2) + i) * OUT);
  #pragma unroll
  for (int i = 0; i < 4; ++i)
    wqb[i] = *reinterpret_cast<const float4*>(wbase + (size_t)(16 + (g2 << 2) + i) * OUT);

  #pragma unroll 1
  for (int c = 0; c < 8; ++c) {
    // ---- sub A: in-chunk rows 0..15 (kq 0/1), from wqa ----
    {
      uint2 pw[4];
      #pragma unroll
      for (int j = 0; j < 4; ++j) {
        pw[j].x = pack2((&wqa[0].x)[j], (&wqa[1].x)[j]);
        pw[j].y = pack2((&wqa[2].x)[j], (&wqa[3].x)[j]);
      }
      if (c < 7) {   // refill for chunk c+1, rows 0..15
        #pragma unroll
        for (int i = 0; i < 4; ++i)
          wqa[i] = *reinterpret_cast<const float4*>(
              wbase + (size_t)(((c + 1) << 5) + (g2 << 2) + i) * OUT);
      }
      #pragma unroll
      for (int j = 0; j < 4; ++j) {
        const int a = slice_addr(wsl, g2 >> 1, (c16 << 2) + j) + ((g2 & 1) << 3);
        *reinterpret_cast<uint2*>(&smem[a]) = pw[j];
      }
    }
    // ---- sub B: in-chunk rows 16..31 (kq 2/3), from wqb ----
    {
      uint2 pw[4];
      #pragma unroll
      for (int j = 0; j < 4; ++j) {
        pw[j].x = pack2((&wqb[0].x)[j], (&wqb[1].x)[j]);
        pw[j].y = pack2((&wqb[2].x)[j], (&wqb[3].x)[j]);
      }
      if (c < 7) {   // refill for chunk c+1, rows 16..31
        #pragma unroll
        for (int i = 0; i < 4; ++i)
          wqb[i] = *reinterpret_cast<const float4*>(
              wbase + (size_t)(((c + 1) << 5) + 16 + (g2 << 2) + i) * OUT);
      }
      #pragma unroll
      for (int j = 0; j < 4; ++j) {
        const int a = slice_addr(wsl, 2 + (g2 >> 1), (c16 << 2) + j) + ((g2 & 1) << 3);
        *reinterpret_cast<uint2*>(&smem[a]) = pw[j];
      }
    }
    // ---- MFMA on chunk c (slice fully written; per-wave LDS ops are in-order) ----
    const int aaddr = ((c16 << 9) + (c << 6) + (g2 << 4)) ^ ((c16 & 7) << 4);
    const short8 af = *reinterpret_cast<const short8*>(&smem[aaddr]);
    #pragma unroll
    for (int t = 0; t < 4; ++t) {
      const short8 bfv = *reinterpret_cast<const short8*>(
          &smem[slice_addr(wsl, g2, (t << 4) + c16)]);
      acc[t] = __builtin_amdgcn_mfma_f32_16x16x32_bf16(af, bfv, acc[t], 0, 0, 0);
    }
  }

  // ---- epilogue: overlay gbuf (g*1040 + b*65 + coll) over whole arena ----
  __syncthreads();   // all waves' slice/xh reads complete before overwrite
  float* gb = reinterpret_cast<float*>(smem);
  #pragma unroll
  for (int t = 0; t < 4; ++t) {
    const int coll = (t << 4) + c16;                    // local col 0..63
    const float bias = bg[(size_t)n * OUT + half * 64 + coll];
    #pragma unroll
    for (int r = 0; r < 4; ++r) {
      const int b = (g2 << 2) + r;                      // C/D: row=(lane>>4)*4+reg
      gb[g * 1040 + b * 65 + coll] = acc[t][r] + bias;
    }
  }
  __syncthreads();

  // ---- combine gates, write ht and ct (fp32 outputs) ----
  const size_t nbase = (size_t)n * OUT;
  #pragma unroll
  for (int r = 0; r < 4; ++r) {
    const int p    = tid + (r << 8);   // 0..1023
    const int b    = p >> 6;
    const int coll = p & 63;
    const int o    = half * 64 + coll;
    const float gi = gb[0 * 1040 + b * 65 + coll];
    const float go = gb[1 * 1040 + b * 65 + coll];
    const float gf = gb[2 * 1040 + b * 65 + coll];
    const float gc = gb[3 * 1040 + b * 65 + coll];
    const float it = fsigmoid(gi);
    const float ot = fsigmoid(go);
    const float ft = fsigmoid(gf);
    const float ch = ftanh(gc);
    const float cp = ct_1[nbase + o];
    const float ct = ft * cp + it * ch;
    const float ht = ot * ftanh(ct);
    const size_t oidx = (size_t)b * ((size_t)NS * OUT) + nbase + o;
    out[oidx] = ht;                              // ht
    out[(size_t)B * NS * OUT + oidx] = ct;       // ct
  }
}
}  // namespace

extern "C" void kernel_launch(void* const* d_in, const int* in_sizes, int n_in,
                              void* d_out, int out_size, void* d_ws, size_t ws_size,
                              hipStream_t stream) {
  const float* xt     = (const float*)d_in[0];
  const float* hidden = (const float*)d_in[1];
  const float* ct_1   = (const float*)d_in[2];
  const float* Wi     = (const float*)d_in[3];
  const float* bi     = (const float*)d_in[4];
  const float* Wo     = (const float*)d_in[5];
  const float* bo     = (const float*)d_in[6];
  const float* Wf     = (const float*)d_in[7];
  const float* bf     = (const float*)d_in[8];
  const float* Wc     = (const float*)d_in[9];
  const float* bc     = (const float*)d_in[10];

  lstm_kernel<<<2 * NS, 256, 0, stream>>>(xt, hidden, ct_1, Wi, bi, Wo, bo,
                                          Wf, bf, Wc, bc,
                                          (float*)d_out);
}

// Round 11
// 109.584 us; speedup vs baseline: 1.1233x; 1.1233x over previous
//
#include <hip/hip_runtime.h>
#include <hip/hip_bf16.h>

namespace {
constexpr int B   = 16;
constexpr int NS  = 1000;
constexpr int IN  = 128;
constexpr int OUT = 128;
constexpr int K   = 256;   // IN + OUT

typedef __attribute__((ext_vector_type(8))) short short8;
typedef __attribute__((ext_vector_type(4))) float f32x4;

__device__ __forceinline__ float fsigmoid(float x) {
  return 1.0f / (1.0f + __expf(-x));
}
__device__ __forceinline__ float ftanh(float x) {
  return 2.0f / (1.0f + __expf(-2.0f * x)) - 1.0f;
}
// fp32 -> bf16 round-to-nearest-even (bit pattern)
__device__ __forceinline__ unsigned int f2bf(float f) {
  unsigned int u = __builtin_bit_cast(unsigned int, f);
  u += 0x7fffu + ((u >> 16) & 1u);
  return u >> 16;
}
__device__ __forceinline__ unsigned int pack2(float lo, float hi) {
  return f2bf(lo) | (f2bf(hi) << 16);
}

// Block = stock n. 8 waves = gate (wid>>1) x col-half (wid&1).
// W path: NO LDS staging — B-fragments loaded directly from global
// (per lane: 8 stride-512B dwords = one k-octet of one column; 16 lanes
// x 4B consecutive = 64B segments, imm-offset folded, 32 loads in flight).
// LDS arena (33024 B):
//   [0,8192)  xh bf16 [16 b][256 k], row stride 512B, byte XOR ((b&7)<<4)
//   epilogue overlay from 0: gbuf f32, idx = g*2064 + b*129 + col
__global__ __launch_bounds__(512, 6) void lstm_kernel(
    const float* __restrict__ xt, const float* __restrict__ hidden,
    const float* __restrict__ ct_1,
    const float* __restrict__ Wi, const float* __restrict__ bi,
    const float* __restrict__ Wo, const float* __restrict__ bo,
    const float* __restrict__ Wf, const float* __restrict__ bfp,
    const float* __restrict__ Wc, const float* __restrict__ bc,
    float* __restrict__ out) {
  __shared__ __align__(16) unsigned char smem[33024];

  const int n   = blockIdx.x;
  const int tid = threadIdx.x;

  // ---- stage xh = concat(xt[:,n,:], hidden[0,n,:]) as bf16, swizzled ----
  {
    const int b  = tid >> 5;        // 0..15
    const int s  = tid & 31;        // 16B segment: k0 = s*8
    const int k0 = s << 3;
    float v[8];
    if (k0 < IN) {
      const float4 a = *reinterpret_cast<const float4*>(xt + ((size_t)b * NS + n) * IN + k0);
      const float4 c = *reinterpret_cast<const float4*>(xt + ((size_t)b * NS + n) * IN + k0 + 4);
      v[0]=a.x; v[1]=a.y; v[2]=a.z; v[3]=a.w; v[4]=c.x; v[5]=c.y; v[6]=c.z; v[7]=c.w;
    } else {
      const float4 a = *reinterpret_cast<const float4*>(hidden + (size_t)n * OUT + (k0 - IN));
      const float4 c = *reinterpret_cast<const float4*>(hidden + (size_t)n * OUT + (k0 - IN) + 4);
      v[0]=a.x; v[1]=a.y; v[2]=a.z; v[3]=a.w; v[4]=c.x; v[5]=c.y; v[6]=c.z; v[7]=c.w;
    }
    uint4 pk;
    pk.x = pack2(v[0], v[1]); pk.y = pack2(v[2], v[3]);
    pk.z = pack2(v[4], v[5]); pk.w = pack2(v[6], v[7]);
    const int addr = ((b << 9) + (s << 4)) ^ ((b & 7) << 4);
    *reinterpret_cast<uint4*>(&smem[addr]) = pk;
  }
  __syncthreads();

  const int wid  = tid >> 6;   // 0..7
  const int g    = wid >> 1;   // gate
  const int half = wid & 1;    // column half (cols half*64 .. +63)
  const int l    = tid & 63;
  const int g2   = l >> 4;     // k-octet 0..3 within 32-chunk
  const int c16  = l & 15;     // fragment column (within 16-col tile)

  const float* Wg = (g == 0) ? Wi : (g == 1) ? Wo : (g == 2) ? Wf : Wc;
  const float* bg = (g == 0) ? bi : (g == 1) ? bo : (g == 2) ? bfp : bc;
  // lane base: row = g2*8, col = half*64 + c16. Chunk c adds c*32 rows.
  // In-chunk offsets j*OUT + t*16 are compile-time -> imm-offset loads.
  const float* wq = Wg + (size_t)n * (K * OUT) + (size_t)(g2 << 3) * OUT + half * 64 + c16;

  f32x4 acc[4] = {f32x4{0,0,0,0}, f32x4{0,0,0,0}, f32x4{0,0,0,0}, f32x4{0,0,0,0}};

  #pragma unroll 1
  for (int c = 0; c < 8; ++c) {
    // 32 independent dword loads (8 k x 4 tiles), all issued before use
    float w[4][8];
    #pragma unroll
    for (int t = 0; t < 4; ++t)
      #pragma unroll
      for (int j = 0; j < 8; ++j)
        w[t][j] = wq[(j << 7) + (t << 4)];
    wq += 32 * OUT;

    // A fragment from LDS: row c16, k = c*32 + g2*8 .. +7
    const int aaddr = ((c16 << 9) + (c << 6) + (g2 << 4)) ^ ((c16 & 7) << 4);
    const short8 af = *reinterpret_cast<const short8*>(&smem[aaddr]);

    // pack to bf16 B-frags and MFMA (t ascending = load order -> partial vmcnt waits)
    #pragma unroll
    for (int t = 0; t < 4; ++t) {
      uint4 bu;
      bu.x = pack2(w[t][0], w[t][1]);
      bu.y = pack2(w[t][2], w[t][3]);
      bu.z = pack2(w[t][4], w[t][5]);
      bu.w = pack2(w[t][6], w[t][7]);
      const short8 bfv = __builtin_bit_cast(short8, bu);
      acc[t] = __builtin_amdgcn_mfma_f32_16x16x32_bf16(af, bfv, acc[t], 0, 0, 0);
    }
  }

  // ---- epilogue: overlay gbuf (idx = g*2064 + b*129 + col) ----
  __syncthreads();   // all xh reads complete before overwrite
  float* gb = reinterpret_cast<float*>(smem);
  #pragma unroll
  for (int t = 0; t < 4; ++t) {
    const int colg = (half << 6) + (t << 4) + c16;       // global col 0..127
    const float bias = bg[(size_t)n * OUT + colg];
    #pragma unroll
    for (int r = 0; r < 4; ++r) {
      const int b = (g2 << 2) + r;                       // C/D: row=(lane>>4)*4+reg
      gb[g * 2064 + b * 129 + colg] = acc[t][r] + bias;
    }
  }
  __syncthreads();

  // ---- combine gates, write ht and ct (fp32 outputs) ----
  const size_t nbase = (size_t)n * OUT;
  #pragma unroll
  for (int r = 0; r < 4; ++r) {
    const int p = tid + (r << 9);   // 0..2047
    const int b = p >> 7;
    const int o = p & 127;
    const float gi = gb[0 * 2064 + b * 129 + o];
    const float go = gb[1 * 2064 + b * 129 + o];
    const float gf = gb[2 * 2064 + b * 129 + o];
    const float gc = gb[3 * 2064 + b * 129 + o];
    const float it = fsigmoid(gi);
    const float ot = fsigmoid(go);
    const float ft = fsigmoid(gf);
    const float ch = ftanh(gc);
    const float cp = ct_1[nbase + o];
    const float ct = ft * cp + it * ch;
    const float ht = ot * ftanh(ct);
    const size_t oidx = (size_t)b * ((size_t)NS * OUT) + nbase + o;
    out[oidx] = ht;                              // ht
    out[(size_t)B * NS * OUT + oidx] = ct;       // ct
  }
}
}  // namespace

extern "C" void kernel_launch(void* const* d_in, const int* in_sizes, int n_in,
                              void* d_out, int out_size, void* d_ws, size_t ws_size,
                              hipStream_t stream) {
  const float* xt     = (const float*)d_in[0];
  const float* hidden = (const float*)d_in[1];
  const float* ct_1   = (const float*)d_in[2];
  const float* Wi     = (const float*)d_in[3];
  const float* bi     = (const float*)d_in[4];
  const float* Wo     = (const float*)d_in[5];
  const float* bo     = (const float*)d_in[6];
  const float* Wf     = (const float*)d_in[7];
  const float* bf     = (const float*)d_in[8];
  const float* Wc     = (const float*)d_in[9];
  const float* bc     = (const float*)d_in[10];

  lstm_kernel<<<NS, 512, 0, stream>>>(xt, hidden, ct_1, Wi, bi, Wo, bo,
                                      Wf, bf, Wc, bc,
                                      (float*)d_out);
}

// Round 12
// 107.976 us; speedup vs baseline: 1.1400x; 1.0149x over previous
//
#include <hip/hip_runtime.h>
#include <hip/hip_bf16.h>

namespace {
constexpr int B   = 16;
constexpr int NS  = 1000;
constexpr int IN  = 128;
constexpr int OUT = 128;
constexpr int K   = 256;   // IN + OUT

typedef __attribute__((ext_vector_type(8))) short short8;
typedef __attribute__((ext_vector_type(4))) float f32x4;

__device__ __forceinline__ float fsigmoid(float x) {
  return 1.0f / (1.0f + __expf(-x));
}
__device__ __forceinline__ float ftanh(float x) {
  return 2.0f / (1.0f + __expf(-2.0f * x)) - 1.0f;
}
// fp32 -> bf16 round-to-nearest-even (bit pattern)
__device__ __forceinline__ unsigned int f2bf(float f) {
  unsigned int u = __builtin_bit_cast(unsigned int, f);
  u += 0x7fffu + ((u >> 16) & 1u);
  return u >> 16;
}
__device__ __forceinline__ unsigned int pack2(float lo, float hi) {
  return f2bf(lo) | (f2bf(hi) << 16);
}

// Block = stock n. 8 waves = gate (wid>>1) x col-half (wid&1).
// W path: per-wave private 8KB LDS buffer filled by global_load_lds (zero
// VGPR cost -> 8x1KB loads in flight per wave, allocator can't serialize).
// Per-lane SOURCE col-rotation (cq + 4*(i>>1)) makes the strided B-frag
// ds_read_b32s exactly 2-way bank aliased (free) with a dense LDS layout.
// A-frags (xt/hidden) read directly from global (32B runs, cache-resident).
// LDS: 8 waves x 8192 = 65536 B; epilogue overlays gbuf f32 (g*2064+b*129+col).
__global__ __launch_bounds__(512, 4) void lstm_kernel(
    const float* __restrict__ xt, const float* __restrict__ hidden,
    const float* __restrict__ ct_1,
    const float* __restrict__ Wi, const float* __restrict__ bi,
    const float* __restrict__ Wo, const float* __restrict__ bo,
    const float* __restrict__ Wf, const float* __restrict__ bfp,
    const float* __restrict__ Wc, const float* __restrict__ bc,
    float* __restrict__ out) {
  __shared__ __align__(16) unsigned char smem[65536];

  const int n   = blockIdx.x;
  const int tid = threadIdx.x;
  const int wid  = tid >> 6;   // 0..7
  const int g    = wid >> 1;   // gate
  const int half = wid & 1;    // column half (cols half*64 .. +63)
  const int l    = tid & 63;
  const int g2   = l >> 4;     // k-octet in frags / row-sub in staging
  const int c16  = l & 15;     // frag column / colquad in staging

  const float* Wg = (g == 0) ? Wi : (g == 1) ? Wo : (g == 2) ? Wf : Wc;
  const float* bg = (g == 0) ? bi : (g == 1) ? bo : (g == 2) ? bfp : bc;

  unsigned char* wbuf = smem + (wid << 13);          // this wave's 8KB buffer
  const float* wcb = Wg + (size_t)n * (K * OUT) + half * 64;

  // ---- stage chunk r (rows r*32..r*32+31, 64 cols, fp32) : 8 global_load_lds
  auto stage_chunk = [&](int r) {
    #pragma unroll
    for (int i = 0; i < 8; ++i) {
      const int cq = (c16 + ((i >> 1) << 2)) & 15;   // source col rotation
      const float* src =
          wcb + (size_t)((r << 5) + (i << 2) + g2) * OUT + (cq << 2);
      __builtin_amdgcn_global_load_lds(
          (const __attribute__((address_space(1))) void*)src,
          (__attribute__((address_space(3))) void*)(wbuf + (i << 10)),
          16, 0, 0);
    }
  };
  // ---- A-frag for chunk r: xh[row=c16][k=r*32+g2*8 .. +7] from global ----
  auto load_a = [&](int r, float4& x0, float4& x1) {
    const int k = (r << 5) + (g2 << 3);
    const float* s = (k < IN) ? (xt + ((size_t)c16 * NS + n) * IN + k)
                              : (hidden + (size_t)n * OUT + (k - IN));
    x0 = *reinterpret_cast<const float4*>(s);
    x1 = *reinterpret_cast<const float4*>(s + 4);
  };

  f32x4 acc[4] = {f32x4{0,0,0,0}, f32x4{0,0,0,0}, f32x4{0,0,0,0}, f32x4{0,0,0,0}};

  stage_chunk(0);
  float4 a0, a1;
  load_a(0, a0, a1);

  #pragma unroll 1
  for (int r = 0; r < 8; ++r) {
    asm volatile("s_waitcnt vmcnt(0)" ::: "memory");   // chunk r + A r resident

    // B-frags: 8 ds_read_b32 per tile; bank = rotated 2-way (free)
    float wv[4][8];
    #pragma unroll
    for (int t = 0; t < 4; ++t) {
      const int pb = (((((t << 2) + (c16 >> 2)) - (g2 << 2)) & 15) << 4) +
                     ((c16 & 3) << 2);
      #pragma unroll
      for (int j = 0; j < 8; ++j)
        wv[t][j] = *reinterpret_cast<const float*>(
            wbuf + (g2 << 11) + (j << 8) + pb);
    }
    uint4 au;
    au.x = pack2(a0.x, a0.y); au.y = pack2(a0.z, a0.w);
    au.z = pack2(a1.x, a1.y); au.w = pack2(a1.z, a1.w);
    const short8 af = __builtin_bit_cast(short8, au);

    asm volatile("s_waitcnt lgkmcnt(0)" ::: "memory"); // ds_reads drained
    float4 na0 = a0, na1 = a1;
    if (r < 7) {
      stage_chunk(r + 1);        // overwrite safe: reads complete
      load_a(r + 1, na0, na1);
    }

    #pragma unroll
    for (int t = 0; t < 4; ++t) {
      uint4 bu;
      bu.x = pack2(wv[t][0], wv[t][1]);
      bu.y = pack2(wv[t][2], wv[t][3]);
      bu.z = pack2(wv[t][4], wv[t][5]);
      bu.w = pack2(wv[t][6], wv[t][7]);
      acc[t] = __builtin_amdgcn_mfma_f32_16x16x32_bf16(
          af, __builtin_bit_cast(short8, bu), acc[t], 0, 0, 0);
    }
    a0 = na0; a1 = na1;          // waits (if any) land after the MFMAs
  }

  // ---- epilogue: overlay gbuf (idx = g*2064 + b*129 + col) ----
  __syncthreads();   // all waves' LDS reads complete before overwrite
  float* gb = reinterpret_cast<float*>(smem);
  #pragma unroll
  for (int t = 0; t < 4; ++t) {
    const int colg = (half << 6) + (t << 4) + c16;     // global col 0..127
    const float bias = bg[(size_t)n * OUT + colg];
    #pragma unroll
    for (int r2 = 0; r2 < 4; ++r2) {
      const int b = (g2 << 2) + r2;                    // C/D: row=(lane>>4)*4+reg
      gb[g * 2064 + b * 129 + colg] = acc[t][r2] + bias;
    }
  }
  __syncthreads();

  // ---- combine gates, write ht and ct (fp32 outputs) ----
  const size_t nbase = (size_t)n * OUT;
  #pragma unroll
  for (int r = 0; r < 4; ++r) {
    const int p = tid + (r << 9);   // 0..2047
    const int b = p >> 7;
    const int o = p & 127;
    const float gi = gb[0 * 2064 + b * 129 + o];
    const float go = gb[1 * 2064 + b * 129 + o];
    const float gf = gb[2 * 2064 + b * 129 + o];
    const float gc = gb[3 * 2064 + b * 129 + o];
    const float it = fsigmoid(gi);
    const float ot = fsigmoid(go);
    const float ft = fsigmoid(gf);
    const float ch = ftanh(gc);
    const float cp = ct_1[nbase + o];
    const float ct = ft * cp + it * ch;
    const float ht = ot * ftanh(ct);
    const size_t oidx = (size_t)b * ((size_t)NS * OUT) + nbase + o;
    out[oidx] = ht;                              // ht
    out[(size_t)B * NS * OUT + oidx] = ct;       // ct
  }
}
}  // namespace

extern "C" void kernel_launch(void* const* d_in, const int* in_sizes, int n_in,
                              void* d_out, int out_size, void* d_ws, size_t ws_size,
                              hipStream_t stream) {
  const float* xt     = (const float*)d_in[0];
  const float* hidden = (const float*)d_in[1];
  const float* ct_1   = (const float*)d_in[2];
  const float* Wi     = (const float*)d_in[3];
  const float* bi     = (const float*)d_in[4];
  const float* Wo     = (const float*)d_in[5];
  const float* bo     = (const float*)d_in[6];
  const float* Wf     = (const float*)d_in[7];
  const float* bf     = (const float*)d_in[8];
  const float* Wc     = (const float*)d_in[9];
  const float* bc     = (const float*)d_in[10];

  lstm_kernel<<<NS, 512, 0, stream>>>(xt, hidden, ct_1, Wi, bi, Wo, bo,
                                      Wf, bf, Wc, bc,
                                      (float*)d_out);
}